// Round 6
// baseline (118.697 us; speedup 1.0000x reference)
//
#include <hip/hip_runtime.h>

// MonotoneActivation: per (b,g) group of ARITY=4 inputs, sort-4, barycentric
// interpolation over the 2^4 lattice, OUT_DIM=4 outputs.
//
// R6 design: full 64 KB params table in LDS per block; each block walks
// WHOLE rows sequentially (512 thr = 2 full 4 KB rows per iter, 32 rows
// per block) so X reads and out writes are perfectly sequential 128 KB
// streams per block -> one DRAM page visit per row instead of 4 (the R5
// chunked layout opened each page 4x from 4 different blocks).
// 512 blocks = exactly 2 resident blocks/CU (64 KB LDS each), one pass.
// LDS layout [e][g]: bank = 4g mod 32, independent of data-dependent e ->
// conflict-free ds_read_b128.

#define GROUPS        256
#define ROWS_PER_BLK  32
#define BATCH         16384
#define NBLOCKS       (BATCH / ROWS_PER_BLK)   // 512 = 2 blocks/CU, 1 pass
#define BLOCK_T       512

typedef float f4 __attribute__((ext_vector_type(4)));

__global__ __launch_bounds__(BLOCK_T, 4) void mono_act_kernel(
    const float* __restrict__ X,
    const float* __restrict__ params,   // [GROUPS, 16, 4] floats
    float* __restrict__ out)            // [BATCH, GROUPS*4]
{
    __shared__ f4 lut[16 * GROUPS];        // 64 KB: lut[e*256 + g]

    const int t = threadIdx.x;

    // ---- stage full params table into LDS, transposed to [e][g] ----
    // global side is a stride-256B gather but the 64 KB table is L2/L3-hot;
    // LDS write side is conflict-free.
    const f4* __restrict__ P = reinterpret_cast<const f4*>(params);
    #pragma unroll
    for (int i = 0; i < 8; ++i) {
        int idx = i * BLOCK_T + t;           // 0..4095 == e*256 + g
        int e   = idx >> 8;
        int g   = idx & (GROUPS - 1);
        lut[idx] = P[(g << 4) + e];
    }
    __syncthreads();

    // ---- compute: 512 threads cover 2 full rows per iteration ----
    const int g     = t & (GROUPS - 1);
    const int rhalf = t >> 8;                // 0 or 1
    const int r0    = blockIdx.x * ROWS_PER_BLK + rhalf;

    const f4* __restrict__ X4 = reinterpret_cast<const f4*>(X) + g;
    f4* __restrict__ O4       = reinterpret_cast<f4*>(out) + g;

    #pragma unroll 4
    for (int k = 0; k < ROWS_PER_BLK / 2; ++k) {
        const size_t roff = (size_t)(r0 + 2 * k) * GROUPS;  // f4 units
        const f4 x = X4[roff];

        float a0 = x.x, a1 = x.y, a2 = x.z, a3 = x.w;
        int i0 = 1, i1 = 2, i2 = 4, i3 = 8;   // 1 << original index

        // stable sorting network (strict >): (0,1)(2,3)(0,2)(1,3)(1,2)
#define CEX(a, b, ia, ib)                                   \
        do {                                                \
            if (a > b) {                                    \
                float _t = a; a = b; b = _t;                \
                int _u = ia; ia = ib; ib = _u;              \
            }                                               \
        } while (0)
        CEX(a0, a1, i0, i1);
        CEX(a2, a3, i2, i3);
        CEX(a0, a2, i0, i2);
        CEX(a1, a3, i1, i3);
        CEX(a1, a2, i1, i2);
#undef CEX

        const float c0 = a0;
        const float c1 = a1 - a0;
        const float c2 = a2 - a1;
        const float c3 = a3 - a2;

        // reversed-cumsum lattice indices; e0==15 -> corner==1.0 (projected)
        const int e3 = i3;
        const int e2 = e3 | i2;
        const int e1 = e2 | i1;

        const f4 p1 = lut[(e1 << 8) + g];
        const f4 p2 = lut[(e2 << 8) + g];
        const f4 p3 = lut[(e3 << 8) + g];

        f4 r;
        r.x = c0 + c1 * p1.x + c2 * p2.x + c3 * p3.x;
        r.y = c0 + c1 * p1.y + c2 * p2.y + c3 * p3.y;
        r.z = c0 + c1 * p1.z + c2 * p2.z + c3 * p3.z;
        r.w = c0 + c1 * p1.w + c2 * p2.w + c3 * p3.w;

        O4[roff] = r;
    }
}

extern "C" void kernel_launch(void* const* d_in, const int* in_sizes, int n_in,
                              void* d_out, int out_size, void* d_ws, size_t ws_size,
                              hipStream_t stream) {
    const float* X      = (const float*)d_in[0];
    const float* params = (const float*)d_in[1];
    float* out          = (float*)d_out;

    mono_act_kernel<<<NBLOCKS, BLOCK_T, 0, stream>>>(X, params, out);
}